// Round 6
// baseline (52.292 us; speedup 1.0000x reference)
//
#include <hip/hip_runtime.h>
#include <math.h>

#define EPSF 1.1920929e-07f

typedef float f4 __attribute__((ext_vector_type(4)));

__device__ __forceinline__ float sigmoid_fast(float v) {
    return 1.0f / (1.0f + __expf(-v));
}
__device__ __forceinline__ float tanh_fast(float x) {
    float ax = fabsf(x);
    float e  = __expf(-2.0f * ax);          // in (0,1], never overflows
    float t  = (1.0f - e) / (1.0f + e);
    return copysignf(t, x);
}
__device__ __forceinline__ float gauss_fast(float i, float m, float sg) {
    float d = (i - m) / sg;
    return __expf(-0.5f * d * d);
}

// ---------------------------------------------------------------------------
// Fully fused, one (b,c,x) plane of 64x64 per block (8192 blocks, 256 thr).
// x-loads are issued FIRST (addresses depend only on blk/tid) so their HBM
// latency hides under the MLP preamble; streaming tail is pure fma + NT store.
// ---------------------------------------------------------------------------
__global__ void __launch_bounds__(256) fused_kernel(
        const float* __restrict__ xin, const float* __restrict__ tab,
        const float* __restrict__ w1,  const float* __restrict__ b1,
        const float* __restrict__ w2,  const float* __restrict__ b2,
        const float* __restrict__ wp,  const float* __restrict__ bp,
        const float* __restrict__ wsg, const float* __restrict__ bsg,
        float* __restrict__ out, int out_last)
{
    __shared__ float emb1[2][32];
    __shared__ float emb2[2][32];
    __shared__ float head[8];
    __shared__ float gys[64];
    __shared__ f4    gz4[16];
    __shared__ float pv_sh, sh_sh;

    const int blk = blockIdx.x;        // b*64*64 + c*64 + x
    const int bc  = blk >> 6;
    const int xi  = blk & 63;
    const int b   = bc >> 6;
    const int c   = bc & 63;
    const int tid = threadIdx.x;

    // ---- issue the block's entire read set immediately ----
    const f4* x4 = (const f4*)(xin + (size_t)blk * 4096);
    f4*       o4 = (f4*)(out + (size_t)blk * 4096);
    f4 x0 = __builtin_nontemporal_load(&x4[tid]);
    f4 x1 = __builtin_nontemporal_load(&x4[tid + 256]);
    f4 x2 = __builtin_nontemporal_load(&x4[tid + 512]);
    f4 x3 = __builtin_nontemporal_load(&x4[tid + 768]);

    // ---- preamble (overlaps with the in-flight loads) ----
    // MLP layer 1: emb1[bb][j] = tanh(tab[bb] @ w1.T + b1)
    if (tid < 64) {
        int bb = tid >> 5, j = tid & 31;
        float acc = b1[j];
        #pragma unroll
        for (int k = 0; k < 6; ++k) acc += tab[bb * 6 + k] * w1[j * 6 + k];
        emb1[bb][j] = tanh_fast(acc);
    }
    __syncthreads();

    // MLP layer 2 (vectorized weight-row reads)
    if (tid < 64) {
        int bb = tid >> 5, j = tid & 31;
        const f4* wr = (const f4*)(w2 + j * 32);
        float acc = b2[j];
        #pragma unroll
        for (int q = 0; q < 8; ++q) {
            f4 wv = wr[q];
            acc += wv.x * emb1[bb][q * 4 + 0] + wv.y * emb1[bb][q * 4 + 1]
                 + wv.z * emb1[bb][q * 4 + 2] + wv.w * emb1[bb][q * 4 + 3];
        }
        emb2[bb][j] = tanh_fast(acc);
    }
    __syncthreads();

    // 8 head values for this (b,c):
    // 0:scale 1:shift 2:mu_a 3:mu_b 4:mu_c   (wp rows q*64+c)
    // 5:sa 6:sb 7:sc                          (ws rows (q-5)*64+c)
    if (tid < 8) {
        const float* W  = (tid < 5) ? wp  : wsg;
        const float* Bv = (tid < 5) ? bp  : bsg;
        int row = ((tid < 5) ? tid : (tid - 5)) * 64 + c;
        const f4* wr = (const f4*)(W + row * 32);
        float acc = Bv[row];
        #pragma unroll
        for (int q = 0; q < 8; ++q) {
            f4 wv = wr[q];
            acc += wv.x * emb2[b][q * 4 + 0] + wv.y * emb2[b][q * 4 + 1]
                 + wv.z * emb2[b][q * 4 + 2] + wv.w * emb2[b][q * 4 + 3];
        }
        head[tid] = acc;
    }
    __syncthreads();

    // gaussian tables + plane constants
    if (tid < 64) {
        float m  = tanh_fast(head[3]) * 32.0f + 31.5f;
        float sg = sigmoid_fast(head[6]) * 3.5f + EPSF;
        gys[tid] = gauss_fast((float)tid, m, sg);
    } else if (tid < 128) {
        int i = tid - 64;
        float m  = tanh_fast(head[4]) * 32.0f + 31.5f;
        float sg = sigmoid_fast(head[7]) * 3.5f + EPSF;
        ((float*)gz4)[i] = gauss_fast((float)i, m, sg);
    } else if (tid == 128) {
        float m  = tanh_fast(head[2]) * 32.0f + 31.5f;
        float sg = sigmoid_fast(head[5]) * 3.5f + EPSF;
        pv_sh = (1.0f - head[0]) * gauss_fast((float)xi, m, sg);
        sh_sh = head[1];
    }

    // block 0 only: l2 = sum of 5 frobenius norms
    if (blk == 0) {
        __shared__ float sq[5][128];
        for (int t = tid; t < 640; t += 256) {
            int q = t / 128, r = t % 128;
            int bb = r >> 6, cc = r & 63;
            const float* W  = (q < 2) ? wp  : wsg;
            const float* Bv = (q < 2) ? bp  : bsg;
            int row = ((q < 2) ? q : (q - 2)) * 64 + cc;
            const f4* wr = (const f4*)(W + row * 32);
            float acc = Bv[row];
            #pragma unroll
            for (int u = 0; u < 8; ++u) {
                f4 wv = wr[u];
                acc += wv.x * emb2[bb][u * 4 + 0] + wv.y * emb2[bb][u * 4 + 1]
                     + wv.z * emb2[bb][u * 4 + 2] + wv.w * emb2[bb][u * 4 + 3];
            }
            if (q >= 2) acc = sigmoid_fast(acc);
            sq[q][r] = acc * acc;
        }
        __syncthreads();
        if (tid == 0) {
            float tot = 0.0f;
            for (int q = 0; q < 5; ++q) {
                float ssum = 0.0f;
                for (int i = 0; i < 128; ++i) ssum += sq[q][i];
                tot += sqrtf(ssum);
            }
            out[out_last] = tot;
        }
    }
    __syncthreads();

    // ---- streaming tail: data already in registers ----
    const float pv = pv_sh;
    const float sh = sh_sh;
    const int   yb = tid >> 4;
    const f4    vz = gz4[tid & 15];
    const float s0 = pv * gys[yb];
    const float s1 = pv * gys[yb + 16];
    const float s2 = pv * gys[yb + 32];
    const float s3 = pv * gys[yb + 48];
    const f4 shv = {sh, sh, sh, sh};

    __builtin_nontemporal_store((vz * x0) * s0 + shv, &o4[tid]);
    __builtin_nontemporal_store((vz * x1) * s1 + shv, &o4[tid + 256]);
    __builtin_nontemporal_store((vz * x2) * s2 + shv, &o4[tid + 512]);
    __builtin_nontemporal_store((vz * x3) * s3 + shv, &o4[tid + 768]);
}

// ---------------------------------------------------------------------------
extern "C" void kernel_launch(void* const* d_in, const int* in_sizes, int n_in,
                              void* d_out, int out_size, void* d_ws, size_t ws_size,
                              hipStream_t stream)
{
    const float* x   = (const float*)d_in[0];
    const float* tab = (const float*)d_in[1];
    const float* w1  = (const float*)d_in[2];
    const float* b1  = (const float*)d_in[3];
    const float* w2  = (const float*)d_in[4];
    const float* b2  = (const float*)d_in[5];
    const float* wp  = (const float*)d_in[6];
    const float* bp  = (const float*)d_in[7];
    const float* wsg = (const float*)d_in[8];
    const float* bsg = (const float*)d_in[9];

    float* out = (float*)d_out;

    fused_kernel<<<2 * 64 * 64, 256, 0, stream>>>(
        x, tab, w1, b1, w2, b2, wp, bp, wsg, bsg, out, out_size - 1);
}